// Round 11
// baseline (223.975 us; speedup 1.0000x reference)
//
#include <hip/hip_runtime.h>
#include <hip/hip_bf16.h>

#define DDIM 128
#define RDIM 32
#define BLK  256
#define XSTR 136   // xs row stride u16 (272 B)
#define HSTR 40    // hs row stride u16 (80 B)

typedef __attribute__((ext_vector_type(8))) short bf16x8;
typedef __attribute__((ext_vector_type(4))) float f32x4;

__device__ __forceinline__ float tanh_fast(float v) {
  float e = __expf(2.f * v);
  return 1.f - 2.f / (e + 1.f);
}
__device__ __forceinline__ float sigmoid_fast(float v) {
  return 1.f / (1.f + __expf(-v));
}
__device__ __forceinline__ unsigned short f2bf(float f) {  // RNE f32->bf16
  unsigned u = __float_as_uint(f);
  u += 0x7fffu + ((u >> 16) & 1u);
  return (unsigned short)(u >> 16);
}
__device__ __forceinline__ float bf2f(unsigned short s) {
  return __uint_as_float(((unsigned)s) << 16);
}
__device__ __forceinline__ unsigned pkbf(float lo, float hi) {  // v_cvt_pk_bf16_f32
  __hip_bfloat162 t2 = __float22bfloat162_rn(make_float2(lo, hi));
  return *reinterpret_cast<unsigned*>(&t2);
}
__device__ __forceinline__ int lower_bound(const int* __restrict__ b, int n, int v) {
  int lo = 0, hi = n;
  while (lo < hi) { int m = (lo + hi) >> 1; if (b[m] < v) lo = m + 1; else hi = m; }
  return lo;
}

// ---------------------------------------------------------------------------
// K0: build bf16 A-fragments of W1^T and W2^T (transposed-GEMM K1).
//   w1tf[frag=mt2*4+kk][lane][8] : W1^T[r=mt2*16+lr][d=kk*32+q*8+j]
//   w2tf[mt][lane][8]            : W2^T[d=mt*16+lr][r=q*8+j]
// A-frag layout (16x16x32): row=l&15, k=(l>>4)*8+j.
// ---------------------------------------------------------------------------
__global__ void k0_prep(const float* __restrict__ w1, const float* __restrict__ w2,
                        unsigned short* __restrict__ w1tf, unsigned short* __restrict__ w2tf)
{
  const int i  = blockIdx.x * blockDim.x + threadIdx.x;   // 0..1023
  const int l  = i & 63;
  const int lr = l & 15, q = l >> 4;
  if (i < 512) {
    const int frag = i >> 6;             // mt2*4+kk
    const int mt2 = frag >> 2, kk = frag & 3;
    bf16x8 v;
    #pragma unroll
    for (int j = 0; j < 8; ++j)
      v[j] = (short)f2bf(w1[(size_t)(kk * 32 + q * 8 + j) * RDIM + mt2 * 16 + lr]);
    *(bf16x8*)&w1tf[(size_t)i * 8] = v;
  } else {
    const int mt = (i - 512) >> 6;
    bf16x8 v;
    #pragma unroll
    for (int j = 0; j < 8; ++j)
      v[j] = (short)f2bf(w2[(size_t)(q * 8 + j) * DDIM + mt * 16 + lr]);
    *(bf16x8*)&w2tf[(size_t)(i - 512) * 8] = v;
  }
}

// ---------------------------------------------------------------------------
// KB: parallel per-graph bounds precompute.
// ---------------------------------------------------------------------------
__global__ void kb_bounds(const int* __restrict__ batch, int* __restrict__ bounds,
                          int N, int G)
{
  const int g = blockIdx.x * blockDim.x + threadIdx.x;
  if (g <= G) bounds[g] = lower_bound(batch, N, g);
}

// ---------------------------------------------------------------------------
// K1a (bisect probe): pure stream cast x fp32 -> xb bf16. Fill-kernel shape.
// ---------------------------------------------------------------------------
__global__ __launch_bounds__(BLK) void k1a_cast(
    const float* __restrict__ x, unsigned short* __restrict__ xb, long n4)
{
  long i = (long)blockIdx.x * BLK + threadIdx.x;
  const long stride = (long)gridDim.x * BLK;
  for (; i < n4; i += stride) {
    float4 v = ((const float4*)x)[i];
    uint2 p; p.x = pkbf(v.x, v.y); p.y = pkbf(v.z, v.w);
    ((uint2*)xb)[i] = p;
  }
}

// ---------------------------------------------------------------------------
// K1b: MLP gate entirely in bf16 domain: x2 = xb*(1+tanh(relu(xb@W1+b1)@W2+b2))
// Wave-autonomous 16-node tiles; transposed MFMA (C/D col = node).
// xf B-frags load DIRECT from xb (no conversion); weights in registers;
// H^T bounce via tiny LDS; gate re-reads xb (L1); LDS-staged contiguous store.
// ---------------------------------------------------------------------------
__global__ __launch_bounds__(BLK, 3) void k1b_mlp(
    const unsigned short* __restrict__ xb,
    const unsigned short* __restrict__ w1tf, const float* __restrict__ b1,
    const unsigned short* __restrict__ w2tf, const float* __restrict__ b2,
    unsigned short* __restrict__ x2, int N)
{
  __shared__ unsigned short xs4[4][16 * XSTR];   // 4 x 4352 B
  __shared__ unsigned short hs4[4][16 * HSTR];   // 4 x 1280 B

  const int t  = threadIdx.x;
  const int l  = t & 63;
  const int wv = t >> 6;
  const int lr = l & 15;
  const int q  = l >> 4;
  const int node0 = (blockIdx.x * 4 + wv) * 16;
  if (node0 >= N) return;
  unsigned short* xs = xs4[wv];
  unsigned short* hs = hs4[wv];

  const int row  = node0 + lr;
  const int rowc = min(row, N - 1);
  const unsigned short* xrow = xb + (size_t)rowc * DDIM;

  // ---- weight A-frags to registers: 16 x 16B/lane coalesced (L2-hot) ----
  bf16x8 w1r[2][4], w2r[8];
  #pragma unroll
  for (int mt2 = 0; mt2 < 2; ++mt2)
    #pragma unroll
    for (int kk = 0; kk < 4; ++kk)
      w1r[mt2][kk] = *(const bf16x8*)&w1tf[(size_t)((mt2 * 4 + kk) * 64 + l) * 8];
  #pragma unroll
  for (int mt = 0; mt < 8; ++mt)
    w2r[mt] = *(const bf16x8*)&w2tf[(size_t)(mt * 64 + l) * 8];

  // ---- B-frags of X^T direct from xb: col=node=lr, k=d=kk*32+q*8+j ----
  bf16x8 xf[4];
  #pragma unroll
  for (int kk = 0; kk < 4; ++kk)
    xf[kk] = *(const bf16x8*)&xrow[kk * 32 + q * 8];

  // ---- gate re-read (bf16, 8B/lane, L1-hot), issued early ----
  uint2 xu[8];
  #pragma unroll
  for (int mt = 0; mt < 8; ++mt)
    xu[mt] = *(const uint2*)&xrow[mt * 16 + q * 4];

  // ---- phase B: H^T = W1^T @ X^T + b1 (2 Mtiles x 4 Ksteps) ----
  f32x4 hacc[2];
  {
    float4 bv0 = *(const float4*)(b1 + q * 4);
    float4 bv1 = *(const float4*)(b1 + 16 + q * 4);
    hacc[0][0] = bv0.x; hacc[0][1] = bv0.y; hacc[0][2] = bv0.z; hacc[0][3] = bv0.w;
    hacc[1][0] = bv1.x; hacc[1][1] = bv1.y; hacc[1][2] = bv1.z; hacc[1][3] = bv1.w;
  }
  #pragma unroll
  for (int kk = 0; kk < 4; ++kk) {
    hacc[0] = __builtin_amdgcn_mfma_f32_16x16x32_bf16(w1r[0][kk], xf[kk], hacc[0], 0, 0, 0);
    hacc[1] = __builtin_amdgcn_mfma_f32_16x16x32_bf16(w1r[1][kk], xf[kk], hacc[1], 0, 0, 0);
  }

  // ---- relu + pack -> hs[node(col)][r(row)]; read back H^T B-frag ----
  #pragma unroll
  for (int mt2 = 0; mt2 < 2; ++mt2) {
    float h0 = fmaxf(hacc[mt2][0], 0.f), h1 = fmaxf(hacc[mt2][1], 0.f);
    float h2 = fmaxf(hacc[mt2][2], 0.f), h3 = fmaxf(hacc[mt2][3], 0.f);
    uint2 p; p.x = pkbf(h0, h1); p.y = pkbf(h2, h3);
    *(uint2*)&hs[lr * HSTR + mt2 * 16 + q * 4] = p;
  }
  bf16x8 ah = *(const bf16x8*)&hs[lr * HSTR + q * 8];   // col=node, k=r

  // ---- phase C: A2^T = W2^T @ H^T (8 Mtiles, K=32) ----
  f32x4 cacc[8];
  #pragma unroll
  for (int mt = 0; mt < 8; ++mt)
    #pragma unroll
    for (int c = 0; c < 4; ++c) cacc[mt][c] = 0.f;
  #pragma unroll
  for (int mt = 0; mt < 8; ++mt)
    cacc[mt] = __builtin_amdgcn_mfma_f32_16x16x32_bf16(w2r[mt], ah, cacc[mt], 0, 0, 0);

  // ---- gate in registers -> xs LDS (row lr, cols mt*16+q*4) ----
  #pragma unroll
  for (int mt = 0; mt < 8; ++mt) {
    float4 bv = *(const float4*)(b2 + mt * 16 + q * 4);
    float x0 = bf2f((unsigned short)(xu[mt].x & 0xffffu));
    float x1 = bf2f((unsigned short)(xu[mt].x >> 16));
    float x2v = bf2f((unsigned short)(xu[mt].y & 0xffffu));
    float x3 = bf2f((unsigned short)(xu[mt].y >> 16));
    float y0 = x0 * (1.f + tanh_fast(cacc[mt][0] + bv.x));
    float y1 = x1 * (1.f + tanh_fast(cacc[mt][1] + bv.y));
    float y2 = x2v * (1.f + tanh_fast(cacc[mt][2] + bv.z));
    float y3 = x3 * (1.f + tanh_fast(cacc[mt][3] + bv.w));
    uint2 p; p.x = pkbf(y0, y1); p.y = pkbf(y2, y3);
    *(uint2*)&xs[lr * XSTR + mt * 16 + q * 4] = p;
  }

  // ---- store: contiguous full rows, 1KB/instruction ----
  #pragma unroll
  for (int k = 0; k < 4; ++k) {
    int idx  = l + k * 64;               // 256 chunks = 16 rows x 16
    int node = idx >> 4, coff = (idx & 15) * 8;
    if (node0 + node < N)
      *(bf16x8*)&x2[(size_t)(node0 + node) * DDIM + coff] =
          *(const bf16x8*)&xs[node * XSTR + coff];
  }
}

// ---------------------------------------------------------------------------
// K3 (fused): per-graph mean -> tg=tanh(mean@W) -> coef pass. Bounds precomp.
// ---------------------------------------------------------------------------
__global__ void k3_graph(
    const unsigned short* __restrict__ x2, const int* __restrict__ bounds,
    const float* __restrict__ W, float* __restrict__ out, int N)
{
  __shared__ __align__(16) float part[8][132];
  __shared__ float meanv[DDIM];
  __shared__ float tgs[DDIM];
  const int g = blockIdx.x, t = threadIdx.x;
  const int lo = bounds[g], hi = bounds[g + 1];
  const int q = t & 31, s = t >> 5;

  // ---- phase 1: segment mean ----
  {
    float acc[4] = {0.f, 0.f, 0.f, 0.f};
    for (int n = lo + s; n < hi; n += 8) {
      ushort4 u = *(const ushort4*)&x2[(size_t)n * DDIM + q * 4];
      acc[0] += bf2f(u.x); acc[1] += bf2f(u.y); acc[2] += bf2f(u.z); acc[3] += bf2f(u.w);
    }
    *(float4*)&part[s][q * 4] = make_float4(acc[0], acc[1], acc[2], acc[3]);
  }
  __syncthreads();
  if (t < DDIM) {
    float m = 0.f;
    #pragma unroll
    for (int s2 = 0; s2 < 8; ++s2) m += part[s2][t];
    float invc = (hi > lo) ? 1.f / (float)(hi - lo) : 0.f;
    meanv[t] = m * invc;
  }
  __syncthreads();

  // ---- phase 2: tg = tanh(mean @ W) ----
  if (t < DDIM) {
    float a = 0.f;
    #pragma unroll 8
    for (int k = 0; k < DDIM; ++k) a = fmaf(meanv[k], W[k * DDIM + t], a);
    tgs[t] = tanh_fast(a);
  }
  __syncthreads();

  // ---- phase 3: coefs = sigmoid(x2 . tg); out = sum coefs*x2 ----
  float4 tg4 = *(const float4*)&tgs[q * 4];
  float tga[4] = {tg4.x, tg4.y, tg4.z, tg4.w};
  float acc[4] = {0.f, 0.f, 0.f, 0.f};
  for (int n = lo + s; n < hi; n += 8) {   // 32 lanes of a shuffle group share n
    ushort4 u = *(const ushort4*)&x2[(size_t)n * DDIM + q * 4];
    float xv[4] = {bf2f(u.x), bf2f(u.y), bf2f(u.z), bf2f(u.w)};
    float p = xv[0] * tga[0] + xv[1] * tga[1] + xv[2] * tga[2] + xv[3] * tga[3];
    #pragma unroll
    for (int off = 16; off >= 1; off >>= 1) p += __shfl_xor(p, off, 64);
    float coef = sigmoid_fast(p);
    #pragma unroll
    for (int c = 0; c < 4; ++c) acc[c] = fmaf(coef, xv[c], acc[c]);
  }
  *(float4*)&part[s][q * 4] = make_float4(acc[0], acc[1], acc[2], acc[3]);
  __syncthreads();

  if (t < DDIM) {
    float m = 0.f;
    #pragma unroll
    for (int s2 = 0; s2 < 8; ++s2) m += part[s2][t];
    out[(size_t)g * DDIM + t] = m;
  }
}

// ---------------------------------------------------------------------------
extern "C" void kernel_launch(void* const* d_in, const int* in_sizes, int n_in,
                              void* d_out, int out_size, void* d_ws, size_t ws_size,
                              hipStream_t stream) {
  const float* x     = (const float*)d_in[0];
  const int*   batch = (const int*)d_in[1];
  const float* w1 = (const float*)d_in[3];
  const float* b1 = (const float*)d_in[4];
  const float* w2 = (const float*)d_in[5];
  const float* b2 = (const float*)d_in[6];
  const float* W  = (const float*)d_in[7];
  float* out = (float*)d_out;

  const int N = in_sizes[0] / DDIM;
  const int G = out_size / DDIM;

  // ws layout: [w1tf 4096 u16][w2tf 4096 u16][bounds G+1 int pad16]
  //            [xb N*128 u16][x2 N*128 u16]
  unsigned short* w1tf = (unsigned short*)d_ws;
  unsigned short* w2tf = w1tf + 4096;
  int* bounds = (int*)(w2tf + 4096);
  size_t boff = (((size_t)(G + 1) * 4) + 15) & ~(size_t)15;
  unsigned short* xb = (unsigned short*)((char*)bounds + boff);
  unsigned short* x2 = xb + (size_t)N * DDIM;
  (void)ws_size; (void)n_in;

  hipLaunchKernelGGL(k0_prep, dim3(4), dim3(BLK), 0, stream, w1, w2, w1tf, w2tf);
  hipLaunchKernelGGL(kb_bounds, dim3((G + 1 + BLK - 1) / BLK), dim3(BLK), 0, stream,
                     batch, bounds, N, G);
  const long n4 = (long)N * DDIM / 4;
  hipLaunchKernelGGL(k1a_cast, dim3(2048), dim3(BLK), 0, stream, x, xb, n4);
  const int grid1 = (N + 63) / 64;          // 64 nodes/block (4 waves x 16)
  hipLaunchKernelGGL(k1b_mlp, dim3(grid1), dim3(BLK), 0, stream,
                     xb, w1tf, b1, w2tf, b2, x2, N);
  hipLaunchKernelGGL(k3_graph, dim3(G), dim3(BLK), 0, stream, x2, bounds, W, out, N);
}

// Round 12
// 145.122 us; speedup vs baseline: 1.5434x; 1.5434x over previous
//
#include <hip/hip_runtime.h>
#include <hip/hip_bf16.h>

#define DDIM 128
#define RDIM 32
#define BLK  256
#define CAP  216    // graph rows cached in LDS (bf16); overflow recomputed
#define XS2  132    // x2s row stride (u16)
#define HSTR 40     // hs row stride (u16)

typedef __attribute__((ext_vector_type(8))) short bf16x8;
typedef __attribute__((ext_vector_type(4))) float f32x4;

__device__ __forceinline__ float tanh_fast(float v) {
  float e = __expf(2.f * v);
  return 1.f - 2.f / (e + 1.f);
}
__device__ __forceinline__ float sigmoid_fast(float v) {
  return 1.f / (1.f + __expf(-v));
}
__device__ __forceinline__ unsigned short f2bf(float f) {  // RNE f32->bf16
  unsigned u = __float_as_uint(f);
  u += 0x7fffu + ((u >> 16) & 1u);
  return (unsigned short)(u >> 16);
}
__device__ __forceinline__ float bf2f(unsigned short s) {
  return __uint_as_float(((unsigned)s) << 16);
}
__device__ __forceinline__ unsigned pkbf(float lo, float hi) {  // v_cvt_pk_bf16_f32
  __hip_bfloat162 t2 = __float22bfloat162_rn(make_float2(lo, hi));
  return *reinterpret_cast<unsigned*>(&t2);
}
__device__ __forceinline__ int lower_bound(const int* __restrict__ b, int n, int v) {
  int lo = 0, hi = n;
  while (lo < hi) { int m = (lo + hi) >> 1; if (b[m] < v) lo = m + 1; else hi = m; }
  return lo;
}

// ---------------------------------------------------------------------------
// K0: build bf16 A-fragments of W1^T and W2^T (transposed-GEMM).
//   w1tf[frag=mt2*4+kk][lane][8] : W1^T[r=mt2*16+lr][d=kk*32+q*8+j]
//   w2tf[mt][lane][8]            : W2^T[d=mt*16+lr][r=q*8+j]
// A-frag layout (16x16x32): row=l&15, k=(l>>4)*8+j.
// ---------------------------------------------------------------------------
__global__ void k0_prep(const float* __restrict__ w1, const float* __restrict__ w2,
                        unsigned short* __restrict__ w1tf, unsigned short* __restrict__ w2tf)
{
  const int i  = blockIdx.x * blockDim.x + threadIdx.x;   // 0..1023
  const int l  = i & 63;
  const int lr = l & 15, q = l >> 4;
  if (i < 512) {
    const int frag = i >> 6;             // mt2*4+kk
    const int mt2 = frag >> 2, kk = frag & 3;
    bf16x8 v;
    #pragma unroll
    for (int j = 0; j < 8; ++j)
      v[j] = (short)f2bf(w1[(size_t)(kk * 32 + q * 8 + j) * RDIM + mt2 * 16 + lr]);
    *(bf16x8*)&w1tf[(size_t)i * 8] = v;
  } else {
    const int mt = (i - 512) >> 6;
    bf16x8 v;
    #pragma unroll
    for (int j = 0; j < 8; ++j)
      v[j] = (short)f2bf(w2[(size_t)(q * 8 + j) * DDIM + mt * 16 + lr]);
    *(bf16x8*)&w2tf[(size_t)(i - 512) * 8] = v;
  }
}

// ---------------------------------------------------------------------------
// KB: parallel per-graph bounds precompute.
// ---------------------------------------------------------------------------
__global__ void kb_bounds(const int* __restrict__ batch, int* __restrict__ bounds,
                          int N, int G)
{
  const int g = blockIdx.x * blockDim.x + threadIdx.x;
  if (g <= G) bounds[g] = lower_bound(batch, N, g);
}

// ---------------------------------------------------------------------------
// K_FUSED: one block per graph. Pass1: MLP gate (transposed MFMA) over the
// graph's rows, x2 -> LDS (bf16, first CAP rows) + register mean-accumulate.
// Then mean -> tg = tanh(mean@W) in LDS. Pass2: coef = sigmoid(x2.tg),
// out = sum coef*x2 from LDS (overflow rows recomputed). x read ONCE from HBM;
// x2 never touches HBM.
// ---------------------------------------------------------------------------
__global__ __launch_bounds__(BLK, 2) void k_fused(
    const float* __restrict__ x,
    const unsigned short* __restrict__ w1tf, const float* __restrict__ b1,
    const unsigned short* __restrict__ w2tf, const float* __restrict__ b2,
    const float* __restrict__ W, const int* __restrict__ bounds,
    float* __restrict__ out, int N)
{
  __shared__ unsigned short x2s[CAP * XS2];      // 57,024 B
  __shared__ unsigned short hs4[4][16 * HSTR];   //  5,120 B
  __shared__ float part[4][132];                 //  2,112 B
  __shared__ float meanv[DDIM];                  //    512 B
  __shared__ float tgs[DDIM];                    //    512 B   (total 65,280)

  const int t  = threadIdx.x;
  const int l  = t & 63;
  const int wv = t >> 6;
  const int lr = l & 15;
  const int q  = l >> 4;
  const int g  = blockIdx.x;
  const int lo = bounds[g], hi = bounds[g + 1];
  const int cnt = hi - lo;
  unsigned short* hs = hs4[wv];

  // ---- weight A-frags to registers (L2-hot, 16 coalesced 16B loads) ----
  bf16x8 w1r[2][4], w2r[8];
  #pragma unroll
  for (int mt2 = 0; mt2 < 2; ++mt2)
    #pragma unroll
    for (int kk = 0; kk < 4; ++kk)
      w1r[mt2][kk] = *(const bf16x8*)&w1tf[(size_t)((mt2 * 4 + kk) * 64 + l) * 8];
  #pragma unroll
  for (int mt = 0; mt < 8; ++mt)
    w2r[mt] = *(const bf16x8*)&w2tf[(size_t)(mt * 64 + l) * 8];

  // ---- MLP for one 16-row wave tile: y[mt][c] = x2[row][mt*16+q*4+c] ----
  auto mlp16 = [&](int tb, float (&y)[8][4]) {
    const int ridx = tb + lr;
    const int rcl  = (ridx < cnt) ? ridx : (cnt > 0 ? cnt - 1 : 0);
    const float* xrow = x + (size_t)(lo + rcl) * DDIM;
    bf16x8 xf[4];
    #pragma unroll
    for (int kk = 0; kk < 4; ++kk) {
      float4 a = *(const float4*)(xrow + kk * 32 + q * 8);
      float4 b = *(const float4*)(xrow + kk * 32 + q * 8 + 4);
      uint4 u;
      u.x = pkbf(a.x, a.y); u.y = pkbf(a.z, a.w);
      u.z = pkbf(b.x, b.y); u.w = pkbf(b.z, b.w);
      xf[kk] = *(bf16x8*)&u;
    }
    f32x4 hacc[2];
    {
      float4 bv0 = *(const float4*)(b1 + q * 4);
      float4 bv1 = *(const float4*)(b1 + 16 + q * 4);
      hacc[0][0] = bv0.x; hacc[0][1] = bv0.y; hacc[0][2] = bv0.z; hacc[0][3] = bv0.w;
      hacc[1][0] = bv1.x; hacc[1][1] = bv1.y; hacc[1][2] = bv1.z; hacc[1][3] = bv1.w;
    }
    #pragma unroll
    for (int kk = 0; kk < 4; ++kk) {
      hacc[0] = __builtin_amdgcn_mfma_f32_16x16x32_bf16(w1r[0][kk], xf[kk], hacc[0], 0, 0, 0);
      hacc[1] = __builtin_amdgcn_mfma_f32_16x16x32_bf16(w1r[1][kk], xf[kk], hacc[1], 0, 0, 0);
    }
    #pragma unroll
    for (int mt2 = 0; mt2 < 2; ++mt2) {
      float h0 = fmaxf(hacc[mt2][0], 0.f), h1 = fmaxf(hacc[mt2][1], 0.f);
      float h2 = fmaxf(hacc[mt2][2], 0.f), h3 = fmaxf(hacc[mt2][3], 0.f);
      uint2 p; p.x = pkbf(h0, h1); p.y = pkbf(h2, h3);
      *(uint2*)&hs[lr * HSTR + mt2 * 16 + q * 4] = p;
    }
    bf16x8 ah = *(const bf16x8*)&hs[lr * HSTR + q * 8];   // col=node, k=r
    f32x4 cacc[8];
    #pragma unroll
    for (int mt = 0; mt < 8; ++mt)
      #pragma unroll
      for (int c = 0; c < 4; ++c) cacc[mt][c] = 0.f;
    #pragma unroll
    for (int mt = 0; mt < 8; ++mt)
      cacc[mt] = __builtin_amdgcn_mfma_f32_16x16x32_bf16(w2r[mt], ah, cacc[mt], 0, 0, 0);
    #pragma unroll
    for (int mt = 0; mt < 8; ++mt) {
      float4 xg = *(const float4*)(xrow + mt * 16 + q * 4);   // L1-hot re-read
      float4 bv = *(const float4*)(b2 + mt * 16 + q * 4);
      y[mt][0] = xg.x * (1.f + tanh_fast(cacc[mt][0] + bv.x));
      y[mt][1] = xg.y * (1.f + tanh_fast(cacc[mt][1] + bv.y));
      y[mt][2] = xg.z * (1.f + tanh_fast(cacc[mt][2] + bv.z));
      y[mt][3] = xg.w * (1.f + tanh_fast(cacc[mt][3] + bv.w));
    }
  };

  // ---- PASS 1: MLP, cache to LDS, accumulate mean ----
  float macc[8][4];
  #pragma unroll
  for (int mt = 0; mt < 8; ++mt)
    #pragma unroll
    for (int c = 0; c < 4; ++c) macc[mt][c] = 0.f;

  for (int it = 0; it * 64 < cnt; ++it) {
    const int tb = it * 64 + wv * 16;
    if (tb >= cnt) continue;
    float y[8][4];
    mlp16(tb, y);
    const int ridx = tb + lr;
    if (ridx < cnt) {
      #pragma unroll
      for (int mt = 0; mt < 8; ++mt) {
        macc[mt][0] += y[mt][0]; macc[mt][1] += y[mt][1];
        macc[mt][2] += y[mt][2]; macc[mt][3] += y[mt][3];
        if (ridx < CAP) {
          uint2 p; p.x = pkbf(y[mt][0], y[mt][1]); p.y = pkbf(y[mt][2], y[mt][3]);
          *(uint2*)&x2s[ridx * XS2 + mt * 16 + q * 4] = p;
        }
      }
    }
  }
  __syncthreads();

  // ---- mean: reduce macc over lr lanes, then across waves via part ----
  #pragma unroll
  for (int mt = 0; mt < 8; ++mt)
    #pragma unroll
    for (int c = 0; c < 4; ++c) {
      float v = macc[mt][c];
      v += __shfl_xor(v, 1, 64);
      v += __shfl_xor(v, 2, 64);
      v += __shfl_xor(v, 4, 64);
      v += __shfl_xor(v, 8, 64);
      macc[mt][c] = v;
    }
  if (lr == 0) {
    #pragma unroll
    for (int mt = 0; mt < 8; ++mt)
      *(float4*)&part[wv][mt * 16 + q * 4] =
          make_float4(macc[mt][0], macc[mt][1], macc[mt][2], macc[mt][3]);
  }
  __syncthreads();
  if (t < DDIM) {
    float m = part[0][t] + part[1][t] + part[2][t] + part[3][t];
    meanv[t] = (cnt > 0) ? m / (float)cnt : 0.f;
  }
  __syncthreads();
  if (t < DDIM) {
    float a = 0.f;
    #pragma unroll 8
    for (int k = 0; k < DDIM; ++k) a = fmaf(meanv[k], W[k * DDIM + t], a);
    tgs[t] = tanh_fast(a);
  }
  __syncthreads();

  // ---- PASS 2: coef = sigmoid(x2 . tg); out += coef * x2 ----
  float tgv[8][4];
  #pragma unroll
  for (int mt = 0; mt < 8; ++mt) {
    float4 tv = *(const float4*)&tgs[mt * 16 + q * 4];
    tgv[mt][0] = tv.x; tgv[mt][1] = tv.y; tgv[mt][2] = tv.z; tgv[mt][3] = tv.w;
  }
  float oacc[8][4];
  #pragma unroll
  for (int mt = 0; mt < 8; ++mt)
    #pragma unroll
    for (int c = 0; c < 4; ++c) oacc[mt][c] = 0.f;

  const int cap2 = cnt < CAP ? cnt : CAP;
  for (int it = 0; it * 64 < cap2; ++it) {
    const int tb = it * 64 + wv * 16;
    if (tb >= cap2) continue;
    const int ridx = tb + lr;
    const bool v = ridx < cap2;
    float xv[8][4];
    #pragma unroll
    for (int mt = 0; mt < 8; ++mt) {
      if (v) {
        uint2 u = *(const uint2*)&x2s[ridx * XS2 + mt * 16 + q * 4];
        xv[mt][0] = bf2f((unsigned short)(u.x & 0xffffu));
        xv[mt][1] = bf2f((unsigned short)(u.x >> 16));
        xv[mt][2] = bf2f((unsigned short)(u.y & 0xffffu));
        xv[mt][3] = bf2f((unsigned short)(u.y >> 16));
      } else {
        xv[mt][0] = xv[mt][1] = xv[mt][2] = xv[mt][3] = 0.f;
      }
    }
    float p = 0.f;
    #pragma unroll
    for (int mt = 0; mt < 8; ++mt)
      #pragma unroll
      for (int c = 0; c < 4; ++c) p = fmaf(xv[mt][c], tgv[mt][c], p);
    p += __shfl_xor(p, 16, 64);
    p += __shfl_xor(p, 32, 64);
    const float coef = sigmoid_fast(p);
    #pragma unroll
    for (int mt = 0; mt < 8; ++mt)
      #pragma unroll
      for (int c = 0; c < 4; ++c) oacc[mt][c] = fmaf(coef, xv[mt][c], oacc[mt][c]);
  }
  // overflow rows (ridx >= CAP): recompute MLP, same update
  for (int it = 0; CAP + it * 64 < cnt; ++it) {
    const int tb = CAP + it * 64 + wv * 16;
    if (tb >= cnt) continue;
    float y[8][4];
    mlp16(tb, y);
    const int ridx = tb + lr;
    const bool v = ridx < cnt;
    float p = 0.f;
    if (v) {
      #pragma unroll
      for (int mt = 0; mt < 8; ++mt)
        #pragma unroll
        for (int c = 0; c < 4; ++c) p = fmaf(y[mt][c], tgv[mt][c], p);
    }
    p += __shfl_xor(p, 16, 64);
    p += __shfl_xor(p, 32, 64);
    const float coef = v ? sigmoid_fast(p) : 0.f;
    #pragma unroll
    for (int mt = 0; mt < 8; ++mt)
      #pragma unroll
      for (int c = 0; c < 4; ++c) oacc[mt][c] = fmaf(coef, v ? y[mt][c] : 0.f, oacc[mt][c]);
  }
  __syncthreads();

  // ---- out: reduce oacc over lr lanes, then across waves via part ----
  #pragma unroll
  for (int mt = 0; mt < 8; ++mt)
    #pragma unroll
    for (int c = 0; c < 4; ++c) {
      float v = oacc[mt][c];
      v += __shfl_xor(v, 1, 64);
      v += __shfl_xor(v, 2, 64);
      v += __shfl_xor(v, 4, 64);
      v += __shfl_xor(v, 8, 64);
      oacc[mt][c] = v;
    }
  if (lr == 0) {
    #pragma unroll
    for (int mt = 0; mt < 8; ++mt)
      *(float4*)&part[wv][mt * 16 + q * 4] =
          make_float4(oacc[mt][0], oacc[mt][1], oacc[mt][2], oacc[mt][3]);
  }
  __syncthreads();
  if (t < DDIM)
    out[(size_t)g * DDIM + t] = part[0][t] + part[1][t] + part[2][t] + part[3][t];
}

// ---------------------------------------------------------------------------
extern "C" void kernel_launch(void* const* d_in, const int* in_sizes, int n_in,
                              void* d_out, int out_size, void* d_ws, size_t ws_size,
                              hipStream_t stream) {
  const float* x     = (const float*)d_in[0];
  const int*   batch = (const int*)d_in[1];
  const float* w1 = (const float*)d_in[3];
  const float* b1 = (const float*)d_in[4];
  const float* w2 = (const float*)d_in[5];
  const float* b2 = (const float*)d_in[6];
  const float* W  = (const float*)d_in[7];
  float* out = (float*)d_out;

  const int N = in_sizes[0] / DDIM;
  const int G = out_size / DDIM;

  // ws layout: [w1tf 4096 u16][w2tf 4096 u16][bounds G+1 int]
  unsigned short* w1tf = (unsigned short*)d_ws;
  unsigned short* w2tf = w1tf + 4096;
  int* bounds = (int*)(w2tf + 4096);
  (void)ws_size; (void)n_in;

  hipLaunchKernelGGL(k0_prep, dim3(4), dim3(BLK), 0, stream, w1, w2, w1tf, w2tf);
  hipLaunchKernelGGL(kb_bounds, dim3((G + 1 + BLK - 1) / BLK), dim3(BLK), 0, stream,
                     batch, bounds, N, G);
  hipLaunchKernelGGL(k_fused, dim3(G), dim3(BLK), 0, stream,
                     x, w1tf, b1, w2tf, b2, W, bounds, out, N);
}